// Round 2
// baseline (203.389 us; speedup 1.0000x reference)
//
#include <hip/hip_runtime.h>
#include <cmath>

// Shapes fixed by reference: R=4096, F=256, K=8.
#define R 4096
#define F 256
#define NK 8

typedef _Float16 half8 __attribute__((ext_vector_type(8)));
typedef _Float16 half4v __attribute__((ext_vector_type(4)));
typedef float f32x4 __attribute__((ext_vector_type(4)));

#define LOG2E      1.4426950408889634f
#define LOG2LOG2E  0.5287663729448977f   // log2(log2(e))

// ---------------------------------------------------------------------------
// ws layout (bytes):
//   0          : x1h (4096*256 f16) 2 MB
//   2 MB       : x2h (4096*256 f16) 2 MB
//   4 MB +0    : S   (8*4096 f32)  softmax denominators (phase-0 atomics)
//       +128K  : rA  (8*4096 f32)  c_k*(sq1-2m r1+Fm^2)+log2log2e
//       +256K  : cB  (8*4096 f32)  c_k*(sq2+2m r2)
//       +384K  : prm (16 f32) [0..7]=w_k  [8..15]=g_k = 2*is2*log2e
// Math: c_k = -log2e/(2 s_k^2); t = rA[k][i]+cB[k][j]+g_k*dot,  g_k = -2 c_k
//       exp(kv) = exp2(exp2(t)).  dist in [~150,~6600] so ref clamps never bind.
//
// R6 structure: ONE GEMM. Phase 0 spills raw dot through `out` (64 MB, NT
// stores) while accumulating S. finalize_kernel then rewrites `out` in place
// (same thread reads dot & writes result -> race-free), streaming 128 MB at
// full occupancy. Grid-wide cooperative sync was tried (R5) and cost ~380 MB
// of HBM spin/coherence traffic on gfx950 -- do not reintroduce.
// ---------------------------------------------------------------------------

__global__ __launch_bounds__(256) void prep_kernel(
    const float* __restrict__ x1, const float* __restrict__ x2,
    const float* __restrict__ sigmas, const float* __restrict__ means,
    const float* __restrict__ sigp,
    _Float16* __restrict__ x1h, _Float16* __restrict__ x2h,
    float* __restrict__ rA, float* __restrict__ cB,
    float* __restrict__ S, float* __restrict__ prm)
{
    const int tid  = threadIdx.x;
    const int wid  = tid >> 6;
    const int lane = tid & 63;
    const int row  = blockIdx.x * 4 + wid;   // 0..8191: x1 rows then x2 rows

    const float* src; _Float16* dsth; int r; bool isX1;
    if (row < R) { src = x1; dsth = x1h; r = row;     isX1 = true;  }
    else         { src = x2; dsth = x2h; r = row - R; isX1 = false; }

    float4 v = ((const float4*)(src + (size_t)r * F))[lane];
    half4v h = { (_Float16)v.x, (_Float16)v.y, (_Float16)v.z, (_Float16)v.w };
    *(half4v*)(dsth + (size_t)r * F + lane * 4) = h;

    float s = v.x + v.y + v.z + v.w;
    float q = v.x * v.x + v.y * v.y + v.z * v.z + v.w * v.w;
    for (int m = 1; m < 64; m <<= 1) {
        s += __shfl_xor(s, m);
        q += __shfl_xor(q, m);
    }
    if (lane < NK) {
        int k = lane;
        float sg = sigmas[k], m = means[k];
        float c  = -LOG2E / (2.f * sg * sg);         // c_k
        if (isX1) rA[k * R + r] = c * (q - 2.f * m * s + (float)F * m * m) + LOG2LOG2E;
        else      cB[k * R + r] = c * (q + 2.f * m * s);
    }

    int g = blockIdx.x * 256 + tid;
    if (g < NK * R) S[g] = 0.f;   // ws re-poisoned 0xAA each call

    if (blockIdx.x == 0 && tid == 0) {
        float w[NK], mx = -1e30f;
        for (int k = 0; k < NK; ++k) { float sp = sigp[k]; w[k] = 1.f / (sp * sp); mx = fmaxf(mx, w[k]); }
        float sum = 0.f;
        for (int k = 0; k < NK; ++k) { w[k] = expf(w[k] - mx); sum += w[k]; }
        for (int k = 0; k < NK; ++k) prm[k] = w[k] / sum;
        for (int k = 0; k < NK; ++k) {
            float sg = sigmas[k];
            prm[8 + k] = LOG2E / (sg * sg);     // g_k = 2*is2*log2e
        }
    }
}

// ---------------------------------------------------------------------------
// Single GEMM pass: 128x128-tile fp16 MFMA (dot = x1 @ x2^T).
// Epilogue: (a) NT-store raw dot into `out` (finalize reads it in place),
//           (b) S[k,i] += sum_j exp2(exp2(t))  (quad-shuffle + atomicAdd).
// Epilogue keeps the proven R4 shape (VGPR=64 -> 3+ blocks/CU).
// ---------------------------------------------------------------------------
__global__ __launch_bounds__(256, 2) void gemm_phase0(
    const _Float16* __restrict__ Ah, const _Float16* __restrict__ Bh,
    const float* __restrict__ rA, const float* __restrict__ cB,
    const float* __restrict__ prm, float* __restrict__ S, float* __restrict__ out)
{
    constexpr int SK = 72;  // 64 + 8-half pad: 2-way bank alias (free)
    __shared__ _Float16 As[128 * SK];
    __shared__ _Float16 Bs[128 * SK];

    const int tid  = threadIdx.x;
    const int lane = tid & 63;
    const int wid  = tid >> 6;
    const int wm   = wid >> 1, wn = wid & 1;   // 2x2 waves of 64x64
    const int q    = lane >> 4, m16 = lane & 15;
    const int tm   = blockIdx.y, tn = blockIdx.x;

    f32x4 acc[4][4];
#pragma unroll
    for (int a = 0; a < 4; ++a)
#pragma unroll
        for (int b = 0; b < 4; ++b)
            acc[a][b] = (f32x4){0.f, 0.f, 0.f, 0.f};

    for (int k0 = 0; k0 < F; k0 += 64) {
#pragma unroll
        for (int c = 0; c < 4; ++c) {
            int idx = c * 256 + tid;         // 0..1023 chunks of 8 halves
            int row = idx >> 3, c8 = (idx & 7) * 8;
            *(uint4*)&As[row * SK + c8] =
                *(const uint4*)&Ah[(size_t)(tm * 128 + row) * F + k0 + c8];
            *(uint4*)&Bs[row * SK + c8] =
                *(const uint4*)&Bh[(size_t)(tn * 128 + row) * F + k0 + c8];
        }
        __syncthreads();
#pragma unroll
        for (int s = 0; s < 2; ++s) {
            half8 a[4], b[4];
#pragma unroll
            for (int mt = 0; mt < 4; ++mt)
                a[mt] = *(const half8*)&As[(wm * 64 + mt * 16 + m16) * SK + s * 32 + q * 8];
#pragma unroll
            for (int nt = 0; nt < 4; ++nt)
                b[nt] = *(const half8*)&Bs[(wn * 64 + nt * 16 + m16) * SK + s * 32 + q * 8];
#pragma unroll
            for (int mt = 0; mt < 4; ++mt)
#pragma unroll
                for (int nt = 0; nt < 4; ++nt)
                    acc[mt][nt] = __builtin_amdgcn_mfma_f32_16x16x32_f16(
                        a[mt], b[nt], acc[mt][nt], 0, 0, 0);
        }
        __syncthreads();
    }

    // ---- epilogue: spill dot + accumulate S ----
    float g[8];
#pragma unroll
    for (int k = 0; k < 8; ++k) g[k] = prm[8 + k];   // uniform -> SGPR

    int colg[4];
    float colQ[8][4];
#pragma unroll
    for (int nt = 0; nt < 4; ++nt) {
        colg[nt] = tn * 128 + wn * 64 + nt * 16 + m16;
#pragma unroll
        for (int k = 0; k < 8; ++k) colQ[k][nt] = cB[k * R + colg[nt]];
    }

#pragma unroll
    for (int mt = 0; mt < 4; ++mt) {
#pragma unroll
        for (int r = 0; r < 4; ++r) {
            int rowg = tm * 128 + wm * 64 + mt * 16 + q * 4 + r;

            // raw dot -> out (finalize_kernel rewrites these in place)
#pragma unroll
            for (int nt = 0; nt < 4; ++nt)
                __builtin_nontemporal_store(acc[mt][nt][r],
                                            &out[(size_t)rowg * R + colg[nt]]);

            float rAv[8];
#pragma unroll
            for (int k = 0; k < 8; ++k) rAv[k] = rA[k * R + rowg];
#pragma unroll
            for (int k = 0; k < 8; ++k) {
                float t = 0.f;
#pragma unroll
                for (int nt = 0; nt < 4; ++nt) {
                    float tt = fmaf(g[k], acc[mt][nt][r], rAv[k] + colQ[k][nt]);
                    t += __builtin_amdgcn_exp2f(__builtin_amdgcn_exp2f(tt));
                }
                t += __shfl_xor(t, 1); t += __shfl_xor(t, 2);
                t += __shfl_xor(t, 4); t += __shfl_xor(t, 8);
                if (m16 == 0) atomicAdd(&S[k * R + rowg], t);
            }
        }
    }
}

// ---------------------------------------------------------------------------
// In-place finalize: out[i,j] = sum_k w_k*rcp(S[k,i])*exp2(exp2(t(dot))).
// Each thread reads its own dot (float4) and overwrites the same address.
// Wave layout: 64 lanes cover 256 consecutive j (coalesced 1 KB/row-step);
// per-wave i is uniform -> rA/S loads scalarize. cB tile lives in 32 VGPRs.
// No LDS, ~64 VGPR -> high occupancy; 128 MB streaming, BW-bound.
// ---------------------------------------------------------------------------
__global__ __launch_bounds__(256) void finalize_kernel(
    const float* __restrict__ rA, const float* __restrict__ cB,
    const float* __restrict__ prm, const float* __restrict__ S,
    float* __restrict__ out)
{
    const int lane = threadIdx.x & 63;
    const int w    = threadIdx.x >> 6;
    const int i0   = blockIdx.y * 64 + w * 16;      // wave: 16 rows
    const int j0   = blockIdx.x * 256 + lane * 4;   // wave: 256 cols

    float g[8], wk[8];
#pragma unroll
    for (int k = 0; k < 8; ++k) { g[k] = prm[8 + k]; wk[k] = prm[k]; }

    f32x4 cb[8];
#pragma unroll
    for (int k = 0; k < 8; ++k) cb[k] = *(const f32x4*)&cB[k * R + j0];

    for (int r = 0; r < 16; ++r) {
        int i = i0 + r;
        float ra[8], sv[8];
#pragma unroll
        for (int k = 0; k < 8; ++k) {
            ra[k] = rA[k * R + i];
            sv[k] = wk[k] * __builtin_amdgcn_rcpf(S[k * R + i]);
        }
        f32x4 d = __builtin_nontemporal_load((const f32x4*)&out[(size_t)i * R + j0]);
        f32x4 o = (f32x4){0.f, 0.f, 0.f, 0.f};
#pragma unroll
        for (int k = 0; k < 8; ++k) {
#pragma unroll
            for (int e = 0; e < 4; ++e) {
                float tt = fmaf(g[k], d[e], ra[k] + cb[k][e]);
                o[e] = fmaf(sv[k], __builtin_amdgcn_exp2f(__builtin_amdgcn_exp2f(tt)), o[e]);
            }
        }
        __builtin_nontemporal_store(o, (f32x4*)&out[(size_t)i * R + j0]);
    }
}

extern "C" void kernel_launch(void* const* d_in, const int* in_sizes, int n_in,
                              void* d_out, int out_size, void* d_ws, size_t ws_size,
                              hipStream_t stream) {
    (void)in_sizes; (void)n_in; (void)out_size; (void)ws_size;
    const float* x1     = (const float*)d_in[0];
    const float* x2     = (const float*)d_in[1];
    const float* sigmas = (const float*)d_in[2];
    const float* means  = (const float*)d_in[3];
    const float* sigp   = (const float*)d_in[4];
    float* out = (float*)d_out;

    char* ws = (char*)d_ws;
    _Float16* x1h = (_Float16*)ws;
    _Float16* x2h = (_Float16*)(ws + 2097152);
    float* S   = (float*)(ws + 4194304);
    float* rA  = (float*)(ws + 4194304 + 131072);
    float* cB  = (float*)(ws + 4194304 + 262144);
    float* prm = (float*)(ws + 4194304 + 393216);

    prep_kernel<<<2048, 256, 0, stream>>>(x1, x2, sigmas, means, sigp,
                                          x1h, x2h, rA, cB, S, prm);
    gemm_phase0<<<dim3(32, 32), 256, 0, stream>>>(x1h, x2h, rA, cB, prm, S, out);
    finalize_kernel<<<dim3(16, 64), 256, 0, stream>>>(rA, cB, prm, S, out);
}

// Round 4
// 196.532 us; speedup vs baseline: 1.0349x; 1.0349x over previous
//
#include <hip/hip_runtime.h>
#include <cmath>

// Shapes fixed by reference: R=4096, F=256, K=8.
#define R 4096
#define F 256
#define NK 8

typedef _Float16 half8 __attribute__((ext_vector_type(8)));
typedef _Float16 half4v __attribute__((ext_vector_type(4)));
typedef float f32x4 __attribute__((ext_vector_type(4)));

#define LOG2E      1.4426950408889634f
#define LOG2LOG2E  0.5287663729448977f   // log2(log2(e))

// ---------------------------------------------------------------------------
// ws layout (bytes):
//   0          : x1h (4096*256 f16) 2 MB
//   2 MB       : x2h (4096*256 f16) 2 MB
//   4 MB +0    : S   (8*4096 f32)  softmax denominators (phase-0 atomics)
//       +128K  : rA  (8*4096 f32)  c_k*(sq1-2m r1+Fm^2)+log2log2e
//       +256K  : cB  (8*4096 f32)  c_k*(sq2+2m r2)
//       +384K  : prm (16 f32) [0..7]=w_k  [8..15]=g_k = 2*is2*log2e
// Math: c_k = -log2e/(2 s_k^2); t = rA[k][i]+cB[k][j]+g_k*dot,  g_k = -2 c_k
//       exp(kv) = exp2(exp2(t)).  dist in [~150,~6600] so ref clamps never bind.
//
// Structure: ONE GEMM. Phase 0 spills raw dot through `out` (regular cached
// stores -> L2/L3; NT stores cost +29us in R6, do not reintroduce), while
// accumulating S via DPP row-reduction + atomics. finalize then rewrites
// `out` in place (same thread reads dot & writes result -> race-free),
// streaming through the 256MB L3. Grid-wide cooperative sync (R5) cost
// ~380 MB of HBM spin/coherence traffic -- do not reintroduce.
// ---------------------------------------------------------------------------

__global__ __launch_bounds__(256) void prep_kernel(
    const float* __restrict__ x1, const float* __restrict__ x2,
    const float* __restrict__ sigmas, const float* __restrict__ means,
    const float* __restrict__ sigp,
    _Float16* __restrict__ x1h, _Float16* __restrict__ x2h,
    float* __restrict__ rA, float* __restrict__ cB,
    float* __restrict__ S, float* __restrict__ prm)
{
    const int tid  = threadIdx.x;
    const int wid  = tid >> 6;
    const int lane = tid & 63;
    const int row  = blockIdx.x * 4 + wid;   // 0..8191: x1 rows then x2 rows

    const float* src; _Float16* dsth; int r; bool isX1;
    if (row < R) { src = x1; dsth = x1h; r = row;     isX1 = true;  }
    else         { src = x2; dsth = x2h; r = row - R; isX1 = false; }

    float4 v = ((const float4*)(src + (size_t)r * F))[lane];
    half4v h = { (_Float16)v.x, (_Float16)v.y, (_Float16)v.z, (_Float16)v.w };
    *(half4v*)(dsth + (size_t)r * F + lane * 4) = h;

    float s = v.x + v.y + v.z + v.w;
    float q = v.x * v.x + v.y * v.y + v.z * v.z + v.w * v.w;
    for (int m = 1; m < 64; m <<= 1) {
        s += __shfl_xor(s, m);
        q += __shfl_xor(q, m);
    }
    if (lane < NK) {
        int k = lane;
        float sg = sigmas[k], m = means[k];
        float c  = -LOG2E / (2.f * sg * sg);         // c_k
        if (isX1) rA[k * R + r] = c * (q - 2.f * m * s + (float)F * m * m) + LOG2LOG2E;
        else      cB[k * R + r] = c * (q + 2.f * m * s);
    }

    int g = blockIdx.x * 256 + tid;
    if (g < NK * R) S[g] = 0.f;   // ws re-poisoned 0xAA each call

    if (blockIdx.x == 0 && tid == 0) {
        float w[NK], mx = -1e30f;
        for (int k = 0; k < NK; ++k) { float sp = sigp[k]; w[k] = 1.f / (sp * sp); mx = fmaxf(mx, w[k]); }
        float sum = 0.f;
        for (int k = 0; k < NK; ++k) { w[k] = expf(w[k] - mx); sum += w[k]; }
        for (int k = 0; k < NK; ++k) prm[k] = w[k] / sum;
        for (int k = 0; k < NK; ++k) {
            float sg = sigmas[k];
            prm[8 + k] = LOG2E / (sg * sg);     // g_k = 2*is2*log2e
        }
    }
}

// DPP-fused add: x + dpp_move(x, CTRL). CTRL must be an ICE -> template arg.
// GCNDPPCombine folds the mov into v_add_f32_dpp (full-rate VALU, no LDS
// traffic, unlike __shfl_xor's ds_swizzle). CTRL: 0xB1=quad_perm xor1,
// 0x4E=quad_perm xor2, 0x124=row_ror:4, 0x128=row_ror:8 (16-lane rows).
template <int CTRL>
__device__ __forceinline__ float dpp_radd(float x) {
    int xi = __builtin_bit_cast(int, x);
    int yi = __builtin_amdgcn_update_dpp(0, xi, CTRL, 0xF, 0xF, true);
    return x + __builtin_bit_cast(float, yi);
}

// ---------------------------------------------------------------------------
// Single GEMM pass: 128x128-tile fp16 MFMA (dot = x1 @ x2^T).
// Epilogue: (a) cached store of raw dot into `out` (finalize reads in place),
//           (b) S[k,i] += sum_j exp2(exp2(t))  (DPP row-reduce + atomicAdd).
// ---------------------------------------------------------------------------
__global__ __launch_bounds__(256, 2) void gemm_phase0(
    const _Float16* __restrict__ Ah, const _Float16* __restrict__ Bh,
    const float* __restrict__ rA, const float* __restrict__ cB,
    const float* __restrict__ prm, float* __restrict__ S, float* __restrict__ out)
{
    constexpr int SK = 72;  // 64 + 8-half pad: 2-way bank alias (free)
    __shared__ _Float16 As[128 * SK];
    __shared__ _Float16 Bs[128 * SK];

    const int tid  = threadIdx.x;
    const int lane = tid & 63;
    const int wid  = tid >> 6;
    const int wm   = wid >> 1, wn = wid & 1;   // 2x2 waves of 64x64
    const int q    = lane >> 4, m16 = lane & 15;
    const int tm   = blockIdx.y, tn = blockIdx.x;

    f32x4 acc[4][4];
#pragma unroll
    for (int a = 0; a < 4; ++a)
#pragma unroll
        for (int b = 0; b < 4; ++b)
            acc[a][b] = (f32x4){0.f, 0.f, 0.f, 0.f};

    for (int k0 = 0; k0 < F; k0 += 64) {
#pragma unroll
        for (int c = 0; c < 4; ++c) {
            int idx = c * 256 + tid;         // 0..1023 chunks of 8 halves
            int row = idx >> 3, c8 = (idx & 7) * 8;
            *(uint4*)&As[row * SK + c8] =
                *(const uint4*)&Ah[(size_t)(tm * 128 + row) * F + k0 + c8];
            *(uint4*)&Bs[row * SK + c8] =
                *(const uint4*)&Bh[(size_t)(tn * 128 + row) * F + k0 + c8];
        }
        __syncthreads();
#pragma unroll
        for (int s = 0; s < 2; ++s) {
            half8 a[4], b[4];
#pragma unroll
            for (int mt = 0; mt < 4; ++mt)
                a[mt] = *(const half8*)&As[(wm * 64 + mt * 16 + m16) * SK + s * 32 + q * 8];
#pragma unroll
            for (int nt = 0; nt < 4; ++nt)
                b[nt] = *(const half8*)&Bs[(wn * 64 + nt * 16 + m16) * SK + s * 32 + q * 8];
#pragma unroll
            for (int mt = 0; mt < 4; ++mt)
#pragma unroll
                for (int nt = 0; nt < 4; ++nt)
                    acc[mt][nt] = __builtin_amdgcn_mfma_f32_16x16x32_f16(
                        a[mt], b[nt], acc[mt][nt], 0, 0, 0);
        }
        __syncthreads();
    }

    // ---- epilogue: spill dot (cached) + accumulate S (DPP reduce) ----
    float g[8];
#pragma unroll
    for (int k = 0; k < 8; ++k) g[k] = prm[8 + k];   // uniform -> SGPR

    int colg[4];
    float colQ[8][4];
#pragma unroll
    for (int nt = 0; nt < 4; ++nt) {
        colg[nt] = tn * 128 + wn * 64 + nt * 16 + m16;
#pragma unroll
        for (int k = 0; k < 8; ++k) colQ[k][nt] = cB[k * R + colg[nt]];
    }

#pragma unroll
    for (int mt = 0; mt < 4; ++mt) {
#pragma unroll
        for (int r = 0; r < 4; ++r) {
            int rowg = tm * 128 + wm * 64 + mt * 16 + q * 4 + r;

            // raw dot -> out, through L2/L3 (finalize rewrites in place)
#pragma unroll
            for (int nt = 0; nt < 4; ++nt)
                out[(size_t)rowg * R + colg[nt]] = acc[mt][nt][r];

            float rAv[8];
#pragma unroll
            for (int k = 0; k < 8; ++k) rAv[k] = rA[k * R + rowg];
#pragma unroll
            for (int k = 0; k < 8; ++k) {
                float t = 0.f;
#pragma unroll
                for (int nt = 0; nt < 4; ++nt) {
                    float tt = fmaf(g[k], acc[mt][nt][r], rAv[k] + colQ[k][nt]);
                    t += __builtin_amdgcn_exp2f(__builtin_amdgcn_exp2f(tt));
                }
                // 16-lane sum, full-rate VALU DPP (no LDS)
                t = dpp_radd<0xB1>(t);    // quad_perm xor1 (1,0,3,2)
                t = dpp_radd<0x4E>(t);    // quad_perm xor2 (2,3,0,1)
                t = dpp_radd<0x124>(t);   // row_ror:4
                t = dpp_radd<0x128>(t);   // row_ror:8
                if (m16 == 0) atomicAdd(&S[k * R + rowg], t);
            }
        }
    }
}

// ---------------------------------------------------------------------------
// In-place finalize: out[i,j] = sum_k w_k*rcp(S[k,i])*exp2(exp2(t(dot))).
// Each thread reads its own dot (float4, cached -> L3 hit) and overwrites the
// same address. Row loop software-pipelined (prefetch next d during compute).
// 2048 blocks, no LDS -> deep TLP for latency hiding.
// ---------------------------------------------------------------------------
__global__ __launch_bounds__(256) void finalize_kernel(
    const float* __restrict__ rA, const float* __restrict__ cB,
    const float* __restrict__ prm, const float* __restrict__ S,
    float* __restrict__ out)
{
    const int lane = threadIdx.x & 63;
    const int w    = threadIdx.x >> 6;
    const int i0   = blockIdx.y * 32 + w * 8;       // wave: 8 rows
    const int j0   = blockIdx.x * 256 + lane * 4;   // wave: 256 cols

    float g[8], wk[8];
#pragma unroll
    for (int k = 0; k < 8; ++k) { g[k] = prm[8 + k]; wk[k] = prm[k]; }

    f32x4 cb[8];
#pragma unroll
    for (int k = 0; k < 8; ++k) cb[k] = *(const f32x4*)&cB[k * R + j0];

    f32x4 d = *(const f32x4*)&out[(size_t)i0 * R + j0];
#pragma unroll
    for (int r = 0; r < 8; ++r) {
        int i = i0 + r;
        f32x4 dn;
        if (r < 7) dn = *(const f32x4*)&out[(size_t)(i + 1) * R + j0];

        float ra[8], sv[8];
#pragma unroll
        for (int k = 0; k < 8; ++k) {
            ra[k] = rA[k * R + i];
            sv[k] = wk[k] * __builtin_amdgcn_rcpf(S[k * R + i]);
        }
        f32x4 o = (f32x4){0.f, 0.f, 0.f, 0.f};
#pragma unroll
        for (int k = 0; k < 8; ++k) {
#pragma unroll
            for (int e = 0; e < 4; ++e) {
                float tt = fmaf(g[k], d[e], ra[k] + cb[k][e]);
                o[e] = fmaf(sv[k], __builtin_amdgcn_exp2f(__builtin_amdgcn_exp2f(tt)), o[e]);
            }
        }
        *(f32x4*)&out[(size_t)i * R + j0] = o;
        d = dn;
    }
}

extern "C" void kernel_launch(void* const* d_in, const int* in_sizes, int n_in,
                              void* d_out, int out_size, void* d_ws, size_t ws_size,
                              hipStream_t stream) {
    (void)in_sizes; (void)n_in; (void)out_size; (void)ws_size;
    const float* x1     = (const float*)d_in[0];
    const float* x2     = (const float*)d_in[1];
    const float* sigmas = (const float*)d_in[2];
    const float* means  = (const float*)d_in[3];
    const float* sigp   = (const float*)d_in[4];
    float* out = (float*)d_out;

    char* ws = (char*)d_ws;
    _Float16* x1h = (_Float16*)ws;
    _Float16* x2h = (_Float16*)(ws + 2097152);
    float* S   = (float*)(ws + 4194304);
    float* rA  = (float*)(ws + 4194304 + 131072);
    float* cB  = (float*)(ws + 4194304 + 262144);
    float* prm = (float*)(ws + 4194304 + 393216);

    prep_kernel<<<2048, 256, 0, stream>>>(x1, x2, sigmas, means, sigp,
                                          x1h, x2h, rA, cB, S, prm);
    gemm_phase0<<<dim3(32, 32), 256, 0, stream>>>(x1h, x2h, rA, cB, prm, S, out);
    finalize_kernel<<<dim3(16, 128), 256, 0, stream>>>(rA, cB, prm, S, out);
}

// Round 5
// 174.708 us; speedup vs baseline: 1.1642x; 1.1249x over previous
//
#include <hip/hip_runtime.h>
#include <cmath>

// Shapes fixed by reference: R=4096, F=256, K=8.
#define R 4096
#define F 256
#define NK 8

typedef _Float16 half8 __attribute__((ext_vector_type(8)));
typedef _Float16 half4v __attribute__((ext_vector_type(4)));
typedef float f32x4 __attribute__((ext_vector_type(4)));

#define LOG2E      1.4426950408889634f
#define LOG2LOG2E  0.5287663729448977f   // log2(log2(e))

// ---------------------------------------------------------------------------
// ws layout (bytes):
//   0          : x1h (4096*256 f16) 2 MB
//   2 MB       : x2h (4096*256 f16) 2 MB
//   4 MB +0    : S   (8*4096 f32)  softmax denominators (phase-0 atomics)
//       +128K  : rA  (8*4096 f32)  c_k*(sq1-2m r1+Fm^2)+log2log2e
//       +256K  : cB  (8*4096 f32)  c_k*(sq2+2m r2)
//       +384K  : prm (16 f32) [0..7]=w_k  [8..15]=g_k = 2*is2*log2e
// Math: c_k = -log2e/(2 s_k^2); t = rA[k][i]+cB[k][j]+g_k*dot,  g_k = -2 c_k
//       exp(kv) = exp2(exp2(t)).  dist in [~150,~6600] so ref clamps never bind.
//
// Structure: two-GEMM (R0 baseline shape). Phase 0 computes S via DPP-reduce
// + atomics; phase 1 re-runs the GEMM and finalizes. FAILED alternatives --
// do not reintroduce:
//  * cooperative grid.sync fusion (R1): +380 MB HBM spin/coherence traffic.
//  * dot spill through `out` (R2/R4): +19us NT or cached -- 64 MB stream
//    writes back to HBM either way, and in-place finalize saves nothing
//    because phase1's GEMM redo is only ~6-8us of real work.
//  * NT stores anywhere (R2): write-drain stall, +29us.
// ---------------------------------------------------------------------------

__global__ __launch_bounds__(256) void prep_kernel(
    const float* __restrict__ x1, const float* __restrict__ x2,
    const float* __restrict__ sigmas, const float* __restrict__ means,
    const float* __restrict__ sigp,
    _Float16* __restrict__ x1h, _Float16* __restrict__ x2h,
    float* __restrict__ rA, float* __restrict__ cB,
    float* __restrict__ S, float* __restrict__ prm)
{
    const int tid  = threadIdx.x;
    const int wid  = tid >> 6;
    const int lane = tid & 63;
    const int row  = blockIdx.x * 4 + wid;   // 0..8191: x1 rows then x2 rows

    const float* src; _Float16* dsth; int r; bool isX1;
    if (row < R) { src = x1; dsth = x1h; r = row;     isX1 = true;  }
    else         { src = x2; dsth = x2h; r = row - R; isX1 = false; }

    float4 v = ((const float4*)(src + (size_t)r * F))[lane];
    half4v h = { (_Float16)v.x, (_Float16)v.y, (_Float16)v.z, (_Float16)v.w };
    *(half4v*)(dsth + (size_t)r * F + lane * 4) = h;

    float s = v.x + v.y + v.z + v.w;
    float q = v.x * v.x + v.y * v.y + v.z * v.z + v.w * v.w;
    for (int m = 1; m < 64; m <<= 1) {
        s += __shfl_xor(s, m);
        q += __shfl_xor(q, m);
    }
    if (lane < NK) {
        int k = lane;
        float sg = sigmas[k], m = means[k];
        float c  = -LOG2E / (2.f * sg * sg);         // c_k
        if (isX1) rA[k * R + r] = c * (q - 2.f * m * s + (float)F * m * m) + LOG2LOG2E;
        else      cB[k * R + r] = c * (q + 2.f * m * s);
    }

    int g = blockIdx.x * 256 + tid;
    if (g < NK * R) S[g] = 0.f;   // ws re-poisoned 0xAA each call

    if (blockIdx.x == 0 && tid == 0) {
        float w[NK], mx = -1e30f;
        for (int k = 0; k < NK; ++k) { float sp = sigp[k]; w[k] = 1.f / (sp * sp); mx = fmaxf(mx, w[k]); }
        float sum = 0.f;
        for (int k = 0; k < NK; ++k) { w[k] = expf(w[k] - mx); sum += w[k]; }
        for (int k = 0; k < NK; ++k) prm[k] = w[k] / sum;
        for (int k = 0; k < NK; ++k) {
            float sg = sigmas[k];
            prm[8 + k] = LOG2E / (sg * sg);     // g_k = 2*is2*log2e
        }
    }
}

// DPP-fused add: x + dpp_move(x, CTRL). CTRL must be an ICE -> template arg.
// Folds to v_add_f32_dpp: full-rate VALU, no LDS/lgkm (unlike __shfl_xor's
// ds_swizzle chains). Verified bit-identical to shfl reduce in R4.
// CTRL: 0xB1=quad_perm xor1, 0x4E=quad_perm xor2, 0x124=row_ror:4,
// 0x128=row_ror:8 (rows of 16 lanes).
template <int CTRL>
__device__ __forceinline__ float dpp_radd(float x) {
    int xi = __builtin_bit_cast(int, x);
    int yi = __builtin_amdgcn_update_dpp(0, xi, CTRL, 0xF, 0xF, true);
    return x + __builtin_bit_cast(float, yi);
}

// ---------------------------------------------------------------------------
// Phase 0: 128x128-tile fp16 MFMA GEMM; epilogue accumulates softmax
// denominators S[k,i] += sum_j exp2(exp2(t)) via DPP reduce + atomicAdd.
// rA loads vectorized: (mt,k) loop order makes rA[k*R+rowb..+3] one f32x4
// (was 128 scalar VMEM loads/thread, now 32 vector loads).
// ---------------------------------------------------------------------------
__global__ __launch_bounds__(256, 2) void gemm_phase0(
    const _Float16* __restrict__ Ah, const _Float16* __restrict__ Bh,
    const float* __restrict__ rA, const float* __restrict__ cB,
    const float* __restrict__ prm, float* __restrict__ S)
{
    constexpr int SK = 72;  // 64 + 8-half pad: 2-way bank alias (free)
    __shared__ _Float16 As[128 * SK];
    __shared__ _Float16 Bs[128 * SK];

    const int tid  = threadIdx.x;
    const int lane = tid & 63;
    const int wid  = tid >> 6;
    const int wm   = wid >> 1, wn = wid & 1;   // 2x2 waves of 64x64
    const int q    = lane >> 4, m16 = lane & 15;
    const int tm   = blockIdx.y, tn = blockIdx.x;

    f32x4 acc[4][4];
#pragma unroll
    for (int a = 0; a < 4; ++a)
#pragma unroll
        for (int b = 0; b < 4; ++b)
            acc[a][b] = (f32x4){0.f, 0.f, 0.f, 0.f};

    for (int k0 = 0; k0 < F; k0 += 64) {
#pragma unroll
        for (int c = 0; c < 4; ++c) {
            int idx = c * 256 + tid;         // 0..1023 chunks of 8 halves
            int row = idx >> 3, c8 = (idx & 7) * 8;
            *(uint4*)&As[row * SK + c8] =
                *(const uint4*)&Ah[(size_t)(tm * 128 + row) * F + k0 + c8];
            *(uint4*)&Bs[row * SK + c8] =
                *(const uint4*)&Bh[(size_t)(tn * 128 + row) * F + k0 + c8];
        }
        __syncthreads();
#pragma unroll
        for (int s = 0; s < 2; ++s) {
            half8 a[4], b[4];
#pragma unroll
            for (int mt = 0; mt < 4; ++mt)
                a[mt] = *(const half8*)&As[(wm * 64 + mt * 16 + m16) * SK + s * 32 + q * 8];
#pragma unroll
            for (int nt = 0; nt < 4; ++nt)
                b[nt] = *(const half8*)&Bs[(wn * 64 + nt * 16 + m16) * SK + s * 32 + q * 8];
#pragma unroll
            for (int mt = 0; mt < 4; ++mt)
#pragma unroll
                for (int nt = 0; nt < 4; ++nt)
                    acc[mt][nt] = __builtin_amdgcn_mfma_f32_16x16x32_f16(
                        a[mt], b[nt], acc[mt][nt], 0, 0, 0);
        }
        __syncthreads();
    }

    // ---- epilogue: S accumulation (DPP reduce, f32x4 rA loads) ----
    float g[8];
#pragma unroll
    for (int k = 0; k < 8; ++k) g[k] = prm[8 + k];   // uniform -> SGPR

    float colQ[8][4];
#pragma unroll
    for (int nt = 0; nt < 4; ++nt) {
        int colg = tn * 128 + wn * 64 + nt * 16 + m16;
#pragma unroll
        for (int k = 0; k < 8; ++k) colQ[k][nt] = cB[k * R + colg];
    }

#pragma unroll
    for (int mt = 0; mt < 4; ++mt) {
        int rowb = tm * 128 + wm * 64 + mt * 16 + q * 4;   // 4-aligned
#pragma unroll
        for (int k = 0; k < 8; ++k) {
            f32x4 ra4 = *(const f32x4*)&rA[k * R + rowb];
#pragma unroll
            for (int r = 0; r < 4; ++r) {
                float t = 0.f;
#pragma unroll
                for (int nt = 0; nt < 4; ++nt) {
                    float tt = fmaf(g[k], acc[mt][nt][r], ra4[r] + colQ[k][nt]);
                    t += __builtin_amdgcn_exp2f(__builtin_amdgcn_exp2f(tt));
                }
                t = dpp_radd<0xB1>(t);    // quad_perm xor1
                t = dpp_radd<0x4E>(t);    // quad_perm xor2
                t = dpp_radd<0x124>(t);   // row_ror:4
                t = dpp_radd<0x128>(t);   // row_ror:8
                if (m16 == 0) atomicAdd(&S[k * R + rowb + r], t);
            }
        }
    }
}

// ---------------------------------------------------------------------------
// Phase 1: identical GEMM; epilogue finalizes
// out[i,j] = sum_k w_k*rcp(S[k,i]) * exp2(exp2(t)).  Proven R0 shape;
// store is plain cached (NT regressed in R2).
// ---------------------------------------------------------------------------
__global__ __launch_bounds__(256, 2) void gemm_phase1(
    const _Float16* __restrict__ Ah, const _Float16* __restrict__ Bh,
    const float* __restrict__ rA, const float* __restrict__ cB,
    const float* __restrict__ prm, const float* __restrict__ S,
    float* __restrict__ out)
{
    constexpr int SK = 72;
    __shared__ _Float16 As[128 * SK];
    __shared__ _Float16 Bs[128 * SK];

    const int tid  = threadIdx.x;
    const int lane = tid & 63;
    const int wid  = tid >> 6;
    const int wm   = wid >> 1, wn = wid & 1;
    const int q    = lane >> 4, m16 = lane & 15;
    const int tm   = blockIdx.y, tn = blockIdx.x;

    f32x4 acc[4][4];
#pragma unroll
    for (int a = 0; a < 4; ++a)
#pragma unroll
        for (int b = 0; b < 4; ++b)
            acc[a][b] = (f32x4){0.f, 0.f, 0.f, 0.f};

    for (int k0 = 0; k0 < F; k0 += 64) {
#pragma unroll
        for (int c = 0; c < 4; ++c) {
            int idx = c * 256 + tid;
            int row = idx >> 3, c8 = (idx & 7) * 8;
            *(uint4*)&As[row * SK + c8] =
                *(const uint4*)&Ah[(size_t)(tm * 128 + row) * F + k0 + c8];
            *(uint4*)&Bs[row * SK + c8] =
                *(const uint4*)&Bh[(size_t)(tn * 128 + row) * F + k0 + c8];
        }
        __syncthreads();
#pragma unroll
        for (int s = 0; s < 2; ++s) {
            half8 a[4], b[4];
#pragma unroll
            for (int mt = 0; mt < 4; ++mt)
                a[mt] = *(const half8*)&As[(wm * 64 + mt * 16 + m16) * SK + s * 32 + q * 8];
#pragma unroll
            for (int nt = 0; nt < 4; ++nt)
                b[nt] = *(const half8*)&Bs[(wn * 64 + nt * 16 + m16) * SK + s * 32 + q * 8];
#pragma unroll
            for (int mt = 0; mt < 4; ++mt)
#pragma unroll
                for (int nt = 0; nt < 4; ++nt)
                    acc[mt][nt] = __builtin_amdgcn_mfma_f32_16x16x32_f16(
                        a[mt], b[nt], acc[mt][nt], 0, 0, 0);
        }
        __syncthreads();
    }

    // ---- epilogue: finalize (R4-proven shape, cached store) ----
    float g[8], wv[8];
#pragma unroll
    for (int k = 0; k < 8; ++k) { g[k] = prm[8 + k]; wv[k] = prm[k]; }

    int colg[4];
    float colQ[8][4];
#pragma unroll
    for (int nt = 0; nt < 4; ++nt) {
        colg[nt] = tn * 128 + wn * 64 + nt * 16 + m16;
#pragma unroll
        for (int k = 0; k < 8; ++k) colQ[k][nt] = cB[k * R + colg[nt]];
    }

#pragma unroll
    for (int mt = 0; mt < 4; ++mt) {
#pragma unroll
        for (int r = 0; r < 4; ++r) {
            int rowg = tm * 128 + wm * 64 + mt * 16 + q * 4 + r;
            float rAv[8];
#pragma unroll
            for (int k = 0; k < 8; ++k) rAv[k] = rA[k * R + rowg];
            float sv[8];
#pragma unroll
            for (int k = 0; k < 8; ++k)
                sv[k] = wv[k] * __builtin_amdgcn_rcpf(S[k * R + rowg]);
#pragma unroll
            for (int nt = 0; nt < 4; ++nt) {
                float d = acc[mt][nt][r];
                float o = 0.f;
#pragma unroll
                for (int k = 0; k < 8; ++k) {
                    float tt = fmaf(g[k], d, rAv[k] + colQ[k][nt]);
                    o = fmaf(sv[k], __builtin_amdgcn_exp2f(__builtin_amdgcn_exp2f(tt)), o);
                }
                out[(size_t)rowg * R + colg[nt]] = o;
            }
        }
    }
}

extern "C" void kernel_launch(void* const* d_in, const int* in_sizes, int n_in,
                              void* d_out, int out_size, void* d_ws, size_t ws_size,
                              hipStream_t stream) {
    (void)in_sizes; (void)n_in; (void)out_size; (void)ws_size;
    const float* x1     = (const float*)d_in[0];
    const float* x2     = (const float*)d_in[1];
    const float* sigmas = (const float*)d_in[2];
    const float* means  = (const float*)d_in[3];
    const float* sigp   = (const float*)d_in[4];
    float* out = (float*)d_out;

    char* ws = (char*)d_ws;
    _Float16* x1h = (_Float16*)ws;
    _Float16* x2h = (_Float16*)(ws + 2097152);
    float* S   = (float*)(ws + 4194304);
    float* rA  = (float*)(ws + 4194304 + 131072);
    float* cB  = (float*)(ws + 4194304 + 262144);
    float* prm = (float*)(ws + 4194304 + 393216);

    prep_kernel<<<2048, 256, 0, stream>>>(x1, x2, sigmas, means, sigp,
                                          x1h, x2h, rA, cB, S, prm);
    gemm_phase0<<<dim3(32, 32), 256, 0, stream>>>(x1h, x2h, rA, cB, prm, S);
    gemm_phase1<<<dim3(32, 32), 256, 0, stream>>>(x1h, x2h, rA, cB, prm, S, out);
}